// Round 1
// baseline (1320.968 us; speedup 1.0000x reference)
//
#include <hip/hip_runtime.h>
#include <hip/hip_bf16.h>
#include <math.h>

#define B_    8
#define CIN_  256
#define C_    128
#define NPIX_ 16384
#define NT_   64
#define TPB_  4
#define OUTER_ 64
#define BN_EPS_ 1e-5f
#define EPS_   1e-12f

__device__ __forceinline__ float softplus_f(float x) {
    // matches jax.nn.softplus = logaddexp(x, 0)
    return fmaxf(x, 0.f) + log1pf(expf(-fabsf(x)));
}

struct PrepPtrs {
    const float* w[5];
    const float* g[5];
    const float* be[5];
    const float* mu[5];
    const float* va[5];
    float* wout[5];
    float* bout[5];
};

// Fold BN scale/shift into weights + bias. conv order: 0=k1,1=v,2=q1 (cin=256), 3=k2,4=q2 (cin=128)
__global__ void prep_kernel(PrepPtrs p) {
    int idx = blockIdx.x * 256 + threadIdx.x;
    if (idx < 131072) {
        int conv, local, cin;
        if (idx < 32768)       { conv = 0; local = idx;          cin = 256; }
        else if (idx < 65536)  { conv = 1; local = idx - 32768;  cin = 256; }
        else if (idx < 98304)  { conv = 2; local = idx - 65536;  cin = 256; }
        else if (idx < 114688) { conv = 3; local = idx - 98304;  cin = 128; }
        else                   { conv = 4; local = idx - 114688; cin = 128; }
        int o = local / cin;
        float scale = p.g[conv][o] * rsqrtf(p.va[conv][o] + BN_EPS_);
        p.wout[conv][local] = p.w[conv][local] * scale;
    } else if (idx < 131712) {
        int j = idx - 131072;
        int conv = j >> 7;
        int o = j & 127;
        float scale = p.g[conv][o] * rsqrtf(p.va[conv][o] + BN_EPS_);
        p.bout[conv][o] = p.be[conv][o] - p.mu[conv][o] * scale;
    }
}

// Source branch: value=relu(Wv x+bv), h=relu(Wk1 x+bk1), key=softplus(Wk2 h+bk2),
// partial S += value key^T, partial Z += rowsum(key). key/value never hit HBM.
__global__ __launch_bounds__(256, 2)
void src_kernel(const float* __restrict__ src,
                const float* __restrict__ Wk1, const float* __restrict__ bk1,
                const float* __restrict__ Wv,  const float* __restrict__ bv,
                const float* __restrict__ Wk2, const float* __restrict__ bk2,
                float* __restrict__ Spart, float* __restrict__ Zpart)
{
    __shared__ __align__(16) char smem[56320];
    float (*xs)[64]  = (float(*)[64])(smem);                            // 4 KB
    float (*wsa)[17] = (float(*)[17])(smem + 4096);                     // 8.5 KB (pad 17 -> conflict-free)
    float (*wsb)[17] = (float(*)[17])(smem + 12800);                    // 8.5 KB
    __hip_bfloat16 (*hb)[72]  = (__hip_bfloat16(*)[72])(smem + 21504);  // 18 KB, 144B rows (16B aligned)
    __hip_bfloat16 (*kT)[128] = (__hip_bfloat16(*)[128])(smem + 21504); // aliases hb (post-sync)
    __hip_bfloat16 (*vT)[128] = (__hip_bfloat16(*)[128])(smem + 39936); // 16 KB

    const int tid = threadIdx.x;
    const int b   = blockIdx.y;
    const int r0  = (tid >> 3) * 4;   // conv output rows
    const int c0  = (tid & 7) * 8;    // conv output cols (n)
    const int sr0 = (tid & 15) * 8;   // S rows (value channel)
    const int sd0 = (tid >> 4) * 8;   // S cols (key channel)

    float Sacc[8][8];
    #pragma unroll
    for (int i = 0; i < 8; i++)
        #pragma unroll
        for (int j = 0; j < 8; j++) Sacc[i][j] = 0.f;
    float Zacc[8] = {0.f,0.f,0.f,0.f,0.f,0.f,0.f,0.f};

    for (int tt = 0; tt < TPB_; ++tt) {
        const int n0 = (blockIdx.x * TPB_ + tt) * NT_;
        float accA[4][8], accB[4][8];
        #pragma unroll
        for (int i = 0; i < 4; i++)
            #pragma unroll
            for (int j = 0; j < 8; j++) { accA[i][j] = 0.f; accB[i][j] = 0.f; }

        // P1: two CIN=256 convs sharing the x tile
        for (int k0 = 0; k0 < CIN_; k0 += 16) {
            #pragma unroll
            for (int i = 0; i < 4; i++) {
                int id = tid + i * 256;
                int kk = id >> 6, cc = id & 63;
                xs[kk][cc] = src[((size_t)b * CIN_ + (k0 + kk)) * NPIX_ + n0 + cc];
            }
            #pragma unroll
            for (int i = 0; i < 8; i++) {
                int id = tid + i * 256;
                int rr = id >> 4, kk = id & 15;
                wsa[rr][kk] = Wk1[rr * CIN_ + k0 + kk];
                wsb[rr][kk] = Wv[rr * CIN_ + k0 + kk];
            }
            __syncthreads();
            #pragma unroll
            for (int k = 0; k < 16; k++) {
                float xa[8];
                float4 x0 = *(const float4*)&xs[k][c0];
                float4 x1 = *(const float4*)&xs[k][c0 + 4];
                xa[0]=x0.x; xa[1]=x0.y; xa[2]=x0.z; xa[3]=x0.w;
                xa[4]=x1.x; xa[5]=x1.y; xa[6]=x1.z; xa[7]=x1.w;
                float wa[4], wb[4];
                #pragma unroll
                for (int i = 0; i < 4; i++) { wa[i] = wsa[r0+i][k]; wb[i] = wsb[r0+i][k]; }
                #pragma unroll
                for (int i = 0; i < 4; i++)
                    #pragma unroll
                    for (int j = 0; j < 8; j++) {
                        accA[i][j] = fmaf(wa[i], xa[j], accA[i][j]);
                        accB[i][j] = fmaf(wb[i], xa[j], accB[i][j]);
                    }
            }
            __syncthreads();
        }
        // P1 epilogue: h -> LDS (bf16), value stays in regs
        #pragma unroll
        for (int i = 0; i < 4; i++) {
            float bA = bk1[r0 + i], bB = bv[r0 + i];
            #pragma unroll
            for (int j = 0; j < 8; j++) {
                hb[r0 + i][c0 + j] = __float2bfloat16(fmaxf(accA[i][j] + bA, 0.f));
                accB[i][j] = fmaxf(accB[i][j] + bB, 0.f);
            }
        }
        __syncthreads();

        // P2: key = softplus(Wk2 h + bk2)
        float accK[4][8];
        #pragma unroll
        for (int i = 0; i < 4; i++)
            #pragma unroll
            for (int j = 0; j < 8; j++) accK[i][j] = 0.f;
        for (int k0 = 0; k0 < C_; k0 += 16) {
            #pragma unroll
            for (int i = 0; i < 8; i++) {
                int id = tid + i * 256;
                int rr = id >> 4, kk = id & 15;
                wsa[rr][kk] = Wk2[rr * C_ + k0 + kk];
            }
            __syncthreads();
            #pragma unroll
            for (int k = 0; k < 16; k++) {
                float xa[8];
                #pragma unroll
                for (int j = 0; j < 8; j++) xa[j] = __bfloat162float(hb[k0 + k][c0 + j]);
                float wa[4];
                #pragma unroll
                for (int i = 0; i < 4; i++) wa[i] = wsa[r0+i][k];
                #pragma unroll
                for (int i = 0; i < 4; i++)
                    #pragma unroll
                    for (int j = 0; j < 8; j++)
                        accK[i][j] = fmaf(wa[i], xa[j], accK[i][j]);
            }
            __syncthreads();
        }
        #pragma unroll
        for (int i = 0; i < 4; i++) {
            float bK = bk2[r0 + i];
            #pragma unroll
            for (int j = 0; j < 8; j++) accK[i][j] = softplus_f(accK[i][j] + bK);
        }
        // transpose key/value into [n][channel] layout (hb reads all done at last sync)
        #pragma unroll
        for (int i = 0; i < 4; i++)
            #pragma unroll
            for (int j = 0; j < 8; j++) {
                kT[c0 + j][r0 + i] = __float2bfloat16(accK[i][j]);
                vT[c0 + j][r0 + i] = __float2bfloat16(accB[i][j]);
            }
        __syncthreads();

        // P3: S += value key^T ; Z += rowsum(key)
        for (int n = 0; n < NT_; n++) {
            float ka[8], va[8];
            #pragma unroll
            for (int j = 0; j < 8; j++) ka[j] = __bfloat162float(kT[n][sd0 + j]);
            #pragma unroll
            for (int i = 0; i < 8; i++) va[i] = __bfloat162float(vT[n][sr0 + i]);
            #pragma unroll
            for (int i = 0; i < 8; i++)
                #pragma unroll
                for (int j = 0; j < 8; j++)
                    Sacc[i][j] = fmaf(va[i], ka[j], Sacc[i][j]);
            if ((tid & 15) == 0) {
                #pragma unroll
                for (int j = 0; j < 8; j++) Zacc[j] += ka[j];
            }
        }
        __syncthreads();
    }

    const size_t pbase = ((size_t)b * OUTER_ + blockIdx.x) * (C_ * C_);
    #pragma unroll
    for (int i = 0; i < 8; i++)
        #pragma unroll
        for (int j = 0; j < 8; j++)
            Spart[pbase + (size_t)(sr0 + i) * C_ + sd0 + j] = Sacc[i][j];
    if ((tid & 15) == 0) {
        const size_t zbase = ((size_t)b * OUTER_ + blockIdx.x) * C_;
        #pragma unroll
        for (int j = 0; j < 8; j++) Zpart[zbase + sd0 + j] = Zacc[j];
    }
}

__global__ void reduce_kernel(const float* __restrict__ Spart, const float* __restrict__ Zpart,
                              float* __restrict__ Sred, float* __restrict__ Zred)
{
    int idx = blockIdx.x * 256 + threadIdx.x;
    if (idx < B_ * C_ * C_) {
        int b = idx >> 14;
        int i = idx & (C_ * C_ - 1);
        float s = 0.f;
        for (int o = 0; o < OUTER_; o++)
            s += Spart[((size_t)b * OUTER_ + o) * (C_ * C_) + i];
        Sred[idx] = s;
    } else if (idx < B_ * C_ * C_ + B_ * C_) {
        int j = idx - B_ * C_ * C_;
        int b = j >> 7;
        int c = j & 127;
        float s = 0.f;
        for (int o = 0; o < OUTER_; o++)
            s += Zpart[((size_t)b * OUTER_ + o) * C_ + c];
        Zred[j] = s;
    }
}

// Target branch: q_h=relu(Wq1 x), query=softplus(Wq2 q_h), out = (S query) / max(Z.query, eps)
__global__ __launch_bounds__(256, 2)
void tgt_kernel(const float* __restrict__ tgt,
                const float* __restrict__ Wq1, const float* __restrict__ bq1,
                const float* __restrict__ Wq2, const float* __restrict__ bq2,
                const float* __restrict__ Sred, const float* __restrict__ Zred,
                float* __restrict__ out)
{
    __shared__ __align__(16) char smem[31232];
    __shared__ float Zs[128];
    float (*xs)[64]  = (float(*)[64])(smem);
    float (*wsa)[17] = (float(*)[17])(smem + 4096);
    __hip_bfloat16 (*hb)[72] = (__hip_bfloat16(*)[72])(smem + 12800);

    const int tid = threadIdx.x;
    const int b   = blockIdx.y;
    const int n0  = blockIdx.x * NT_;
    const int r0  = (tid >> 3) * 4;
    const int c0  = (tid & 7) * 8;

    // P1: q_h
    float accA[4][8];
    #pragma unroll
    for (int i = 0; i < 4; i++)
        #pragma unroll
        for (int j = 0; j < 8; j++) accA[i][j] = 0.f;
    for (int k0 = 0; k0 < CIN_; k0 += 16) {
        #pragma unroll
        for (int i = 0; i < 4; i++) {
            int id = tid + i * 256;
            int kk = id >> 6, cc = id & 63;
            xs[kk][cc] = tgt[((size_t)b * CIN_ + (k0 + kk)) * NPIX_ + n0 + cc];
        }
        #pragma unroll
        for (int i = 0; i < 8; i++) {
            int id = tid + i * 256;
            int rr = id >> 4, kk = id & 15;
            wsa[rr][kk] = Wq1[rr * CIN_ + k0 + kk];
        }
        __syncthreads();
        #pragma unroll
        for (int k = 0; k < 16; k++) {
            float xa[8];
            float4 x0 = *(const float4*)&xs[k][c0];
            float4 x1 = *(const float4*)&xs[k][c0 + 4];
            xa[0]=x0.x; xa[1]=x0.y; xa[2]=x0.z; xa[3]=x0.w;
            xa[4]=x1.x; xa[5]=x1.y; xa[6]=x1.z; xa[7]=x1.w;
            float wa[4];
            #pragma unroll
            for (int i = 0; i < 4; i++) wa[i] = wsa[r0+i][k];
            #pragma unroll
            for (int i = 0; i < 4; i++)
                #pragma unroll
                for (int j = 0; j < 8; j++)
                    accA[i][j] = fmaf(wa[i], xa[j], accA[i][j]);
        }
        __syncthreads();
    }
    #pragma unroll
    for (int i = 0; i < 4; i++) {
        float bA = bq1[r0 + i];
        #pragma unroll
        for (int j = 0; j < 8; j++)
            hb[r0 + i][c0 + j] = __float2bfloat16(fmaxf(accA[i][j] + bA, 0.f));
    }
    __syncthreads();

    // P2: query
    float accK[4][8];
    #pragma unroll
    for (int i = 0; i < 4; i++)
        #pragma unroll
        for (int j = 0; j < 8; j++) accK[i][j] = 0.f;
    for (int k0 = 0; k0 < C_; k0 += 16) {
        #pragma unroll
        for (int i = 0; i < 8; i++) {
            int id = tid + i * 256;
            int rr = id >> 4, kk = id & 15;
            wsa[rr][kk] = Wq2[rr * C_ + k0 + kk];
        }
        __syncthreads();
        #pragma unroll
        for (int k = 0; k < 16; k++) {
            float xa[8];
            #pragma unroll
            for (int j = 0; j < 8; j++) xa[j] = __bfloat162float(hb[k0 + k][c0 + j]);
            float wa[4];
            #pragma unroll
            for (int i = 0; i < 4; i++) wa[i] = wsa[r0+i][k];
            #pragma unroll
            for (int i = 0; i < 4; i++)
                #pragma unroll
                for (int j = 0; j < 8; j++)
                    accK[i][j] = fmaf(wa[i], xa[j], accK[i][j]);
        }
        __syncthreads();
    }
    if (tid < 128) Zs[tid] = Zred[b * C_ + tid];
    #pragma unroll
    for (int i = 0; i < 4; i++) {
        float bK = bq2[r0 + i];
        #pragma unroll
        for (int j = 0; j < 8; j++)
            hb[r0 + i][c0 + j] = __float2bfloat16(softplus_f(accK[i][j] + bK));
    }
    __syncthreads();

    // P3: out = (S q) / max(Z.q, eps); S staged like a weight matrix
    float accO[4][8], dn[8];
    #pragma unroll
    for (int i = 0; i < 4; i++)
        #pragma unroll
        for (int j = 0; j < 8; j++) accO[i][j] = 0.f;
    #pragma unroll
    for (int j = 0; j < 8; j++) dn[j] = 0.f;
    for (int k0 = 0; k0 < C_; k0 += 16) {
        #pragma unroll
        for (int i = 0; i < 8; i++) {
            int id = tid + i * 256;
            int rr = id >> 4, kk = id & 15;
            wsa[rr][kk] = Sred[(size_t)b * (C_ * C_) + rr * C_ + k0 + kk];
        }
        __syncthreads();
        #pragma unroll
        for (int k = 0; k < 16; k++) {
            float xa[8];
            #pragma unroll
            for (int j = 0; j < 8; j++) xa[j] = __bfloat162float(hb[k0 + k][c0 + j]);
            float zk = Zs[k0 + k];
            float sa[4];
            #pragma unroll
            for (int i = 0; i < 4; i++) sa[i] = wsa[r0+i][k];
            #pragma unroll
            for (int i = 0; i < 4; i++)
                #pragma unroll
                for (int j = 0; j < 8; j++)
                    accO[i][j] = fmaf(sa[i], xa[j], accO[i][j]);
            #pragma unroll
            for (int j = 0; j < 8; j++) dn[j] = fmaf(zk, xa[j], dn[j]);
        }
        __syncthreads();
    }
    #pragma unroll
    for (int j = 0; j < 8; j++) dn[j] = fmaxf(dn[j], EPS_);
    #pragma unroll
    for (int i = 0; i < 4; i++) {
        size_t base = ((size_t)b * C_ + r0 + i) * NPIX_ + n0 + c0;
        float4 o0, o1;
        o0.x = accO[i][0] / dn[0]; o0.y = accO[i][1] / dn[1];
        o0.z = accO[i][2] / dn[2]; o0.w = accO[i][3] / dn[3];
        o1.x = accO[i][4] / dn[4]; o1.y = accO[i][5] / dn[5];
        o1.z = accO[i][6] / dn[6]; o1.w = accO[i][7] / dn[7];
        *(float4*)&out[base] = o0;
        *(float4*)&out[base + 4] = o1;
    }
}

extern "C" void kernel_launch(void* const* d_in, const int* in_sizes, int n_in,
                              void* d_out, int out_size, void* d_ws, size_t ws_size,
                              hipStream_t stream)
{
    const float* tgt = (const float*)d_in[0];
    const float* src = (const float*)d_in[1];
    float* ws = (float*)d_ws;
    float* Wk1 = ws;
    float* Wv  = ws + 32768;
    float* Wq1 = ws + 65536;
    float* Wk2 = ws + 98304;
    float* Wq2 = ws + 114688;
    float* bk1 = ws + 131072;
    float* bv  = ws + 131200;
    float* bq1 = ws + 131328;
    float* bk2 = ws + 131456;
    float* bq2 = ws + 131584;
    float* Sred  = ws + 131712;               // 8*16384
    float* Zred  = ws + 262784;               // 8*128
    float* Spart = ws + 263808;               // 512*16384 = 8388608
    float* Zpart = ws + 263808 + 8388608;     // 512*128

    PrepPtrs p;
    p.w[0] = (const float*)d_in[4];  // k_w1
    p.w[1] = (const float*)d_in[6];  // v_w
    p.w[2] = (const float*)d_in[2];  // q_w1
    p.w[3] = (const float*)d_in[5];  // k_w2
    p.w[4] = (const float*)d_in[3];  // q_w2
    const int gbase[5] = {15, 23, 7, 19, 11}; // k1, v, q1, k2, q2 BN param bases
    for (int c = 0; c < 5; c++) {
        p.g[c]  = (const float*)d_in[gbase[c]];
        p.be[c] = (const float*)d_in[gbase[c] + 1];
        p.mu[c] = (const float*)d_in[gbase[c] + 2];
        p.va[c] = (const float*)d_in[gbase[c] + 3];
    }
    p.wout[0] = Wk1; p.wout[1] = Wv; p.wout[2] = Wq1; p.wout[3] = Wk2; p.wout[4] = Wq2;
    p.bout[0] = bk1; p.bout[1] = bv; p.bout[2] = bq1; p.bout[3] = bk2; p.bout[4] = bq2;

    hipLaunchKernelGGL(prep_kernel, dim3(515), dim3(256), 0, stream, p);
    hipLaunchKernelGGL(src_kernel, dim3(OUTER_, B_), dim3(256), 0, stream,
                       src, Wk1, bk1, Wv, bv, Wk2, bk2, Spart, Zpart);
    hipLaunchKernelGGL(reduce_kernel, dim3(516), dim3(256), 0, stream,
                       Spart, Zpart, Sred, Zred);
    hipLaunchKernelGGL(tgt_kernel, dim3(NPIX_ / NT_, B_), dim3(256), 0, stream,
                       tgt, Wq1, bq1, Wq2, bq2, Sred, Zred, (float*)d_out);
}

// Round 2
// 453.852 us; speedup vs baseline: 2.9106x; 2.9106x over previous
//
#include <hip/hip_runtime.h>
#include <math.h>

typedef __attribute__((ext_vector_type(8))) short bf8v;
typedef __attribute__((ext_vector_type(4))) float f4v;

#define B_      8
#define CIN_    256
#define C_      128
#define NPIX_   16384
#define EPS_    1e-12f
#define BN_EPS_ 1e-5f

// workspace byte offsets (all 256-aligned)
#define OFF_WK1  0u          // 128x256 bf16 = 65536 B
#define OFF_WV   65536u
#define OFF_WQ1  131072u
#define OFF_WK2  196608u     // 128x128 bf16 = 32768 B
#define OFF_WQ2  229376u
#define OFF_BIAS 262144u     // 5*128 f32 = 2560 B  [bk1,bv,bq1,bk2,bq2]
#define OFF_S    264704u     // 8*128*128 f32 = 524288 B
#define OFF_Z    788992u     // 8*128 f32 = 4096 B
#define OFF_SBF  793088u     // 8*128*128 bf16 = 262144 B
#define OFF_VAL  1055232u    // 8*128*16384 bf16 = 33554432 B
#define OFF_KEY  34609664u   // 8*128*16384 bf16 = 33554432 B

__device__ __forceinline__ unsigned short f2bf(float f) {
    unsigned u = __float_as_uint(f);
    unsigned r = u + 0x7fffu + ((u >> 16) & 1u);
    return (unsigned short)(r >> 16);
}
__device__ __forceinline__ float lo16(unsigned v){ return __uint_as_float(v << 16); }
__device__ __forceinline__ float hi16(unsigned v){ return __uint_as_float(v & 0xffff0000u); }
__device__ __forceinline__ float softplus_f(float x) {
    return fmaxf(x, 0.f) + __logf(1.f + __expf(-fabsf(x)));
}
__device__ __forceinline__ f4v MFMA(bf8v a, bf8v b, f4v c) {
    return __builtin_amdgcn_mfma_f32_16x16x32_bf16(a, b, c, 0, 0, 0);
}

struct PrepPtrs {
    const float* w[5];
    const float* g[5];
    const float* be[5];
    const float* mu[5];
    const float* va[5];
    unsigned short* wout[5];
    float* bout[5];
};

// Fold BN into weights (bf16) + bias (f32). order: 0=k1,1=v,2=q1 (cin=256), 3=k2,4=q2 (cin=128)
__global__ void prep_kernel(PrepPtrs p) {
    int idx = blockIdx.x * 256 + threadIdx.x;
    if (idx < 131072) {
        int conv, local, sh;
        if (idx < 32768)       { conv = 0; local = idx;          sh = 8; }
        else if (idx < 65536)  { conv = 1; local = idx - 32768;  sh = 8; }
        else if (idx < 98304)  { conv = 2; local = idx - 65536;  sh = 8; }
        else if (idx < 114688) { conv = 3; local = idx - 98304;  sh = 7; }
        else                   { conv = 4; local = idx - 114688; sh = 7; }
        int o = local >> sh;
        float scale = p.g[conv][o] * rsqrtf(p.va[conv][o] + BN_EPS_);
        p.wout[conv][local] = f2bf(p.w[conv][local] * scale);
    } else if (idx < 131712) {
        int j = idx - 131072;
        int conv = j >> 7;
        int o = j & 127;
        float scale = p.g[conv][o] * rsqrtf(p.va[conv][o] + BN_EPS_);
        p.bout[conv][o] = p.be[conv][o] - p.mu[conv][o] * scale;
    }
}

// ---------------- source branch: value & key to HBM (bf16, [b][c][n]) ----------------
__global__ __launch_bounds__(256)
void srcKV(const float* __restrict__ src,
           const unsigned short* __restrict__ Wk1, const unsigned short* __restrict__ Wv,
           const unsigned short* __restrict__ Wk2, const float* __restrict__ bias,
           unsigned short* __restrict__ valg, unsigned short* __restrict__ keyg)
{
    __shared__ __align__(16) char smem[52224];
    unsigned short* xT = (unsigned short*)smem;            // [64 n][264 us] (256 k + 8 pad)
    unsigned short* hT = (unsigned short*)(smem + 33792);  // [64 n][136 us]; region 18432B

    const int tid = threadIdx.x;
    const int L = tid & 63, w = tid >> 6;
    const int lr = L & 15, qd = L >> 4;
    const int b = blockIdx.y;
    const int gn0 = blockIdx.x * 64;
    const int m0 = w * 32;
    const int kbq = qd * 8;
    const float* bk1 = bias + 0;
    const float* bvp = bias + 128;
    const float* bk2 = bias + 384;

    // stage xT: full K=256, transpose fp32->bf16
    #pragma unroll
    for (int s = 0; s < 4; s++) {
        int id = tid + s * 256;
        int n4 = (id & 15) * 4;
        int k0 = (id >> 4) * 4;
        float4 r[4];
        #pragma unroll
        for (int i = 0; i < 4; i++)
            r[i] = *(const float4*)(src + (size_t)(b * 256 + k0 + i) * NPIX_ + gn0 + n4);
        #pragma unroll
        for (int j = 0; j < 4; j++) {
            ushort4 t;
            t.x = f2bf(((const float*)&r[0])[j]);
            t.y = f2bf(((const float*)&r[1])[j]);
            t.z = f2bf(((const float*)&r[2])[j]);
            t.w = f2bf(((const float*)&r[3])[j]);
            *(ushort4*)(xT + (n4 + j) * 264 + k0) = t;
        }
    }
    __syncthreads();

    // P1: h = Wk1*x, val = Wv*x (dual GEMM sharing B frags)
    f4v zz = {0.f, 0.f, 0.f, 0.f};
    f4v hAcc[2][4], vAcc[2][4];
    #pragma unroll
    for (int mt = 0; mt < 2; mt++)
        #pragma unroll
        for (int nt = 0; nt < 4; nt++) { hAcc[mt][nt] = zz; vAcc[mt][nt] = zz; }
    #pragma unroll
    for (int ks = 0; ks < 8; ks++) {
        const int kb = ks * 32 + kbq;
        bf8v a1[2], a2[2], bx[4];
        #pragma unroll
        for (int mt = 0; mt < 2; mt++) {
            a1[mt] = *(const bf8v*)(Wk1 + (m0 + mt * 16 + lr) * 256 + kb);
            a2[mt] = *(const bf8v*)(Wv  + (m0 + mt * 16 + lr) * 256 + kb);
        }
        #pragma unroll
        for (int nt = 0; nt < 4; nt++)
            bx[nt] = *(const bf8v*)(xT + (nt * 16 + lr) * 264 + kb);
        #pragma unroll
        for (int mt = 0; mt < 2; mt++)
            #pragma unroll
            for (int nt = 0; nt < 4; nt++) {
                hAcc[mt][nt] = MFMA(a1[mt], bx[nt], hAcc[mt][nt]);
                vAcc[mt][nt] = MFMA(a2[mt], bx[nt], vAcc[mt][nt]);
            }
    }
    // h epilogue: bias+relu -> hT[n][c] (bf16)
    #pragma unroll
    for (int mt = 0; mt < 2; mt++) {
        const float4 b4 = *(const float4*)(bk1 + m0 + mt * 16 + qd * 4);
        #pragma unroll
        for (int nt = 0; nt < 4; nt++) {
            ushort4 t;
            t.x = f2bf(fmaxf(hAcc[mt][nt][0] + b4.x, 0.f));
            t.y = f2bf(fmaxf(hAcc[mt][nt][1] + b4.y, 0.f));
            t.z = f2bf(fmaxf(hAcc[mt][nt][2] + b4.z, 0.f));
            t.w = f2bf(fmaxf(hAcc[mt][nt][3] + b4.w, 0.f));
            *(ushort4*)(hT + (nt * 16 + lr) * 136 + m0 + mt * 16 + qd * 4) = t;
        }
    }
    __syncthreads();
    // val bias+relu in regs
    #pragma unroll
    for (int mt = 0; mt < 2; mt++) {
        const float4 b4 = *(const float4*)(bvp + m0 + mt * 16 + qd * 4);
        const float* bp = (const float*)&b4;
        #pragma unroll
        for (int nt = 0; nt < 4; nt++)
            #pragma unroll
            for (int r = 0; r < 4; r++)
                vAcc[mt][nt][r] = fmaxf(vAcc[mt][nt][r] + bp[r], 0.f);
    }

    // P2: key = Wk2 * h
    f4v kAcc[2][4];
    #pragma unroll
    for (int mt = 0; mt < 2; mt++)
        #pragma unroll
        for (int nt = 0; nt < 4; nt++) kAcc[mt][nt] = zz;
    #pragma unroll
    for (int ks = 0; ks < 4; ks++) {
        const int kb = ks * 32 + kbq;
        bf8v a[2], bh[4];
        #pragma unroll
        for (int mt = 0; mt < 2; mt++)
            a[mt] = *(const bf8v*)(Wk2 + (m0 + mt * 16 + lr) * 128 + kb);
        #pragma unroll
        for (int nt = 0; nt < 4; nt++)
            bh[nt] = *(const bf8v*)(hT + (nt * 16 + lr) * 136 + kb);
        #pragma unroll
        for (int mt = 0; mt < 2; mt++)
            #pragma unroll
            for (int nt = 0; nt < 4; nt++)
                kAcc[mt][nt] = MFMA(a[mt], bh[nt], kAcc[mt][nt]);
    }
    __syncthreads();  // hT reads done; xT reads long done

    // stage val -> xT region, key -> hT region, layout [c][72us]
    unsigned short* stgV = xT;
    unsigned short* stgK = hT;
    #pragma unroll
    for (int mt = 0; mt < 2; mt++) {
        const float4 b4 = *(const float4*)(bk2 + m0 + mt * 16 + qd * 4);
        const float* bp = (const float*)&b4;
        #pragma unroll
        for (int nt = 0; nt < 4; nt++)
            #pragma unroll
            for (int r = 0; r < 4; r++) {
                int m = m0 + mt * 16 + qd * 4 + r;
                stgV[m * 72 + nt * 16 + lr] = f2bf(vAcc[mt][nt][r]);
                stgK[m * 72 + nt * 16 + lr] = f2bf(softplus_f(kAcc[mt][nt][r] + bp[r]));
            }
    }
    __syncthreads();
    // coalesced copy-out: 2 arrays x 128 rows x 8 x 16B segs
    #pragma unroll
    for (int s = 0; s < 8; s++) {
        int id = tid + s * 256;
        int arr = id >> 10, rem = id & 1023;
        int c = rem >> 3, o = rem & 7;
        const unsigned short* sp = (arr ? stgK : stgV) + c * 72 + o * 8;
        uint4 d = *(const uint4*)sp;
        unsigned short* gp = (arr ? keyg : valg) + (size_t)(b * 128 + c) * NPIX_ + gn0 + o * 8;
        *(uint4*)gp = d;
    }
}

// ---------------- S = val . key^T (split-K over pixels), Z = rowsum(key) ----------------
__global__ __launch_bounds__(256)
void skern(const unsigned short* __restrict__ valg, const unsigned short* __restrict__ keyg,
           float* __restrict__ Sbuf, float* __restrict__ Zbuf)
{
    __shared__ __align__(16) unsigned short vs[128 * 72];
    __shared__ __align__(16) unsigned short ks_[128 * 72];
    const int tid = threadIdx.x;
    const int L = tid & 63, w = tid >> 6;
    const int lr = L & 15, qd = L >> 4;
    const int b = blockIdx.x >> 5, ch = blockIdx.x & 31;
    const size_t nbase = (size_t)ch * 512;
    const int m0 = (w & 1) * 64, n0 = (w >> 1) * 64;

    f4v zz = {0.f, 0.f, 0.f, 0.f};
    f4v acc[4][4];
    #pragma unroll
    for (int mt = 0; mt < 4; mt++)
        #pragma unroll
        for (int nt = 0; nt < 4; nt++) acc[mt][nt] = zz;
    float zacc = 0.f;
    const int zc = tid >> 1, zh = tid & 1;

    for (int wd = 0; wd < 8; wd++) {
        const size_t nw = nbase + wd * 64;
        #pragma unroll
        for (int s = 0; s < 8; s++) {
            int id = tid + s * 256;
            int arr = id >> 10, rem = id & 1023;
            int c = rem >> 3, o = rem & 7;
            const unsigned short* g = (arr ? keyg : valg) + (size_t)(b * 128 + c) * NPIX_ + nw + o * 8;
            uint4 d = *(const uint4*)g;
            *(uint4*)((arr ? ks_ : vs) + c * 72 + o * 8) = d;
        }
        __syncthreads();
        #pragma unroll
        for (int kk = 0; kk < 2; kk++) {
            const int kb = kk * 32 + qd * 8;
            bf8v a[4], bb[4];
            #pragma unroll
            for (int mt = 0; mt < 4; mt++)
                a[mt] = *(const bf8v*)(vs + (m0 + mt * 16 + lr) * 72 + kb);
            #pragma unroll
            for (int nt = 0; nt < 4; nt++)
                bb[nt] = *(const bf8v*)(ks_ + (n0 + nt * 16 + lr) * 72 + kb);
            #pragma unroll
            for (int mt = 0; mt < 4; mt++)
                #pragma unroll
                for (int nt = 0; nt < 4; nt++)
                    acc[mt][nt] = MFMA(a[mt], bb[nt], acc[mt][nt]);
        }
        // Z partial from this key window
        {
            const unsigned short* kr = ks_ + zc * 72 + zh * 32;
            #pragma unroll
            for (int p = 0; p < 4; p++) {
                uint4 t = *(const uint4*)(kr + p * 8);
                zacc += lo16(t.x) + hi16(t.x) + lo16(t.y) + hi16(t.y)
                      + lo16(t.z) + hi16(t.z) + lo16(t.w) + hi16(t.w);
            }
        }
        __syncthreads();
    }
    // commit partials
    #pragma unroll
    for (int mt = 0; mt < 4; mt++)
        #pragma unroll
        for (int nt = 0; nt < 4; nt++)
            #pragma unroll
            for (int r = 0; r < 4; r++) {
                int m = m0 + mt * 16 + qd * 4 + r;
                int cN = n0 + nt * 16 + lr;
                atomicAdd(Sbuf + ((size_t)b * 128 + m) * 128 + cN, acc[mt][nt][r]);
            }
    atomicAdd(Zbuf + b * 128 + zc, zacc);
}

__global__ void cvts(const float* __restrict__ Sbuf, unsigned short* __restrict__ Sbf) {
    int i = blockIdx.x * 256 + threadIdx.x;
    if (i < 131072) Sbf[i] = f2bf(Sbuf[i]);
}

// ---------------- target branch fused: q1 -> q2 -> S.q / max(Z.q,eps) ----------------
__global__ __launch_bounds__(256)
void tgtAttn(const float* __restrict__ tgt,
             const unsigned short* __restrict__ Wq1, const unsigned short* __restrict__ Wq2,
             const float* __restrict__ bias, const unsigned short* __restrict__ Sbf,
             const float* __restrict__ Zbuf, float* __restrict__ out)
{
    __shared__ __align__(16) char smem[51968];
    unsigned short* xT = (unsigned short*)smem;            // [64][264]
    unsigned short* qT = (unsigned short*)(smem + 33792);  // [64][136] holds q_h then query
    float* dn  = (float*)(smem + 33792 + 17408);           // [64]
    float* Zsh = dn + 64;                                  // [128]

    const int tid = threadIdx.x;
    const int L = tid & 63, w = tid >> 6;
    const int lr = L & 15, qd = L >> 4;
    const int b = blockIdx.y;
    const int gn0 = blockIdx.x * 64;
    const int m0 = w * 32;
    const int kbq = qd * 8;
    const float* bq1 = bias + 256;
    const float* bq2 = bias + 512;

    if (tid < 128) Zsh[tid] = Zbuf[b * 128 + tid];
    #pragma unroll
    for (int s = 0; s < 4; s++) {
        int id = tid + s * 256;
        int n4 = (id & 15) * 4;
        int k0 = (id >> 4) * 4;
        float4 r[4];
        #pragma unroll
        for (int i = 0; i < 4; i++)
            r[i] = *(const float4*)(tgt + (size_t)(b * 256 + k0 + i) * NPIX_ + gn0 + n4);
        #pragma unroll
        for (int j = 0; j < 4; j++) {
            ushort4 t;
            t.x = f2bf(((const float*)&r[0])[j]);
            t.y = f2bf(((const float*)&r[1])[j]);
            t.z = f2bf(((const float*)&r[2])[j]);
            t.w = f2bf(((const float*)&r[3])[j]);
            *(ushort4*)(xT + (n4 + j) * 264 + k0) = t;
        }
    }
    __syncthreads();

    // P1: q_h = relu(Wq1*x + b)
    f4v zz = {0.f, 0.f, 0.f, 0.f};
    f4v acc1[2][4];
    #pragma unroll
    for (int mt = 0; mt < 2; mt++)
        #pragma unroll
        for (int nt = 0; nt < 4; nt++) acc1[mt][nt] = zz;
    #pragma unroll
    for (int ks = 0; ks < 8; ks++) {
        const int kb = ks * 32 + kbq;
        bf8v a[2], bx[4];
        #pragma unroll
        for (int mt = 0; mt < 2; mt++)
            a[mt] = *(const bf8v*)(Wq1 + (m0 + mt * 16 + lr) * 256 + kb);
        #pragma unroll
        for (int nt = 0; nt < 4; nt++)
            bx[nt] = *(const bf8v*)(xT + (nt * 16 + lr) * 264 + kb);
        #pragma unroll
        for (int mt = 0; mt < 2; mt++)
            #pragma unroll
            for (int nt = 0; nt < 4; nt++)
                acc1[mt][nt] = MFMA(a[mt], bx[nt], acc1[mt][nt]);
    }
    #pragma unroll
    for (int mt = 0; mt < 2; mt++) {
        const float4 b4 = *(const float4*)(bq1 + m0 + mt * 16 + qd * 4);
        #pragma unroll
        for (int nt = 0; nt < 4; nt++) {
            ushort4 t;
            t.x = f2bf(fmaxf(acc1[mt][nt][0] + b4.x, 0.f));
            t.y = f2bf(fmaxf(acc1[mt][nt][1] + b4.y, 0.f));
            t.z = f2bf(fmaxf(acc1[mt][nt][2] + b4.z, 0.f));
            t.w = f2bf(fmaxf(acc1[mt][nt][3] + b4.w, 0.f));
            *(ushort4*)(qT + (nt * 16 + lr) * 136 + m0 + mt * 16 + qd * 4) = t;
        }
    }
    __syncthreads();

    // P2: query = softplus(Wq2*q_h + b)
    f4v acc2[2][4];
    #pragma unroll
    for (int mt = 0; mt < 2; mt++)
        #pragma unroll
        for (int nt = 0; nt < 4; nt++) acc2[mt][nt] = zz;
    #pragma unroll
    for (int ks = 0; ks < 4; ks++) {
        const int kb = ks * 32 + kbq;
        bf8v a[2], bh[4];
        #pragma unroll
        for (int mt = 0; mt < 2; mt++)
            a[mt] = *(const bf8v*)(Wq2 + (m0 + mt * 16 + lr) * 128 + kb);
        #pragma unroll
        for (int nt = 0; nt < 4; nt++)
            bh[nt] = *(const bf8v*)(qT + (nt * 16 + lr) * 136 + kb);
        #pragma unroll
        for (int mt = 0; mt < 2; mt++)
            #pragma unroll
            for (int nt = 0; nt < 4; nt++)
                acc2[mt][nt] = MFMA(a[mt], bh[nt], acc2[mt][nt]);
    }
    __syncthreads();  // q_h reads done, safe to overwrite qT
    #pragma unroll
    for (int mt = 0; mt < 2; mt++) {
        const float4 b4 = *(const float4*)(bq2 + m0 + mt * 16 + qd * 4);
        const float* bp = (const float*)&b4;
        #pragma unroll
        for (int nt = 0; nt < 4; nt++) {
            ushort4 t;
            t.x = f2bf(softplus_f(acc2[mt][nt][0] + bp[0]));
            t.y = f2bf(softplus_f(acc2[mt][nt][1] + bp[1]));
            t.z = f2bf(softplus_f(acc2[mt][nt][2] + bp[2]));
            t.w = f2bf(softplus_f(acc2[mt][nt][3] + bp[3]));
            *(ushort4*)(qT + (nt * 16 + lr) * 136 + m0 + mt * 16 + qd * 4) = t;
        }
    }
    __syncthreads();

    // fp32 denom: dn[n] = max(sum_d Z[d]*q[d][n], eps)
    if (tid < 64) {
        const unsigned short* qr = qT + tid * 136;
        float s = 0.f;
        #pragma unroll
        for (int d = 0; d < 128; d += 8) {
            uint4 t = *(const uint4*)(qr + d);
            s = fmaf(Zsh[d + 0], lo16(t.x), s);
            s = fmaf(Zsh[d + 1], hi16(t.x), s);
            s = fmaf(Zsh[d + 2], lo16(t.y), s);
            s = fmaf(Zsh[d + 3], hi16(t.y), s);
            s = fmaf(Zsh[d + 4], lo16(t.z), s);
            s = fmaf(Zsh[d + 5], hi16(t.z), s);
            s = fmaf(Zsh[d + 6], lo16(t.w), s);
            s = fmaf(Zsh[d + 7], hi16(t.w), s);
        }
        dn[tid] = fmaxf(s, EPS_);
    }

    // P3: out = S.q
    f4v oacc[2][4];
    #pragma unroll
    for (int mt = 0; mt < 2; mt++)
        #pragma unroll
        for (int nt = 0; nt < 4; nt++) oacc[mt][nt] = zz;
    #pragma unroll
    for (int ks = 0; ks < 4; ks++) {
        const int kb = ks * 32 + kbq;
        bf8v a[2], bq[4];
        #pragma unroll
        for (int mt = 0; mt < 2; mt++)
            a[mt] = *(const bf8v*)(Sbf + (size_t)b * 16384 + (m0 + mt * 16 + lr) * 128 + kb);
        #pragma unroll
        for (int nt = 0; nt < 4; nt++)
            bq[nt] = *(const bf8v*)(qT + (nt * 16 + lr) * 136 + kb);
        #pragma unroll
        for (int mt = 0; mt < 2; mt++)
            #pragma unroll
            for (int nt = 0; nt < 4; nt++)
                oacc[mt][nt] = MFMA(a[mt], bq[nt], oacc[mt][nt]);
    }
    __syncthreads();

    float inv[4];
    #pragma unroll
    for (int nt = 0; nt < 4; nt++) inv[nt] = 1.f / dn[nt * 16 + lr];
    #pragma unroll
    for (int mt = 0; mt < 2; mt++)
        #pragma unroll
        for (int nt = 0; nt < 4; nt++)
            #pragma unroll
            for (int r = 0; r < 4; r++) {
                int m = m0 + mt * 16 + qd * 4 + r;
                out[(size_t)(b * 128 + m) * NPIX_ + gn0 + nt * 16 + lr] = oacc[mt][nt][r] * inv[nt];
            }
}

extern "C" void kernel_launch(void* const* d_in, const int* in_sizes, int n_in,
                              void* d_out, int out_size, void* d_ws, size_t ws_size,
                              hipStream_t stream)
{
    const float* tgt = (const float*)d_in[0];
    const float* src = (const float*)d_in[1];
    char* ws = (char*)d_ws;
    unsigned short* Wk1 = (unsigned short*)(ws + OFF_WK1);
    unsigned short* Wv  = (unsigned short*)(ws + OFF_WV);
    unsigned short* Wq1 = (unsigned short*)(ws + OFF_WQ1);
    unsigned short* Wk2 = (unsigned short*)(ws + OFF_WK2);
    unsigned short* Wq2 = (unsigned short*)(ws + OFF_WQ2);
    float* bias = (float*)(ws + OFF_BIAS);
    float* Sbuf = (float*)(ws + OFF_S);
    float* Zbuf = (float*)(ws + OFF_Z);
    unsigned short* Sbf = (unsigned short*)(ws + OFF_SBF);
    unsigned short* valg = (unsigned short*)(ws + OFF_VAL);
    unsigned short* keyg = (unsigned short*)(ws + OFF_KEY);

    PrepPtrs p;
    p.w[0] = (const float*)d_in[4];  // k_w1
    p.w[1] = (const float*)d_in[6];  // v_w
    p.w[2] = (const float*)d_in[2];  // q_w1
    p.w[3] = (const float*)d_in[5];  // k_w2
    p.w[4] = (const float*)d_in[3];  // q_w2
    const int gbase[5] = {15, 23, 7, 19, 11}; // k1, v, q1, k2, q2 BN bases
    for (int c = 0; c < 5; c++) {
        p.g[c]  = (const float*)d_in[gbase[c]];
        p.be[c] = (const float*)d_in[gbase[c] + 1];
        p.mu[c] = (const float*)d_in[gbase[c] + 2];
        p.va[c] = (const float*)d_in[gbase[c] + 3];
    }
    p.wout[0] = Wk1; p.wout[1] = Wv; p.wout[2] = Wq1; p.wout[3] = Wk2; p.wout[4] = Wq2;
    p.bout[0] = bias; p.bout[1] = bias + 128; p.bout[2] = bias + 256;
    p.bout[3] = bias + 384; p.bout[4] = bias + 512;

    hipMemsetAsync(ws + OFF_S, 0, 524288 + 4096, stream);
    hipLaunchKernelGGL(prep_kernel, dim3(515), dim3(256), 0, stream, p);
    hipLaunchKernelGGL(srcKV, dim3(256, 8), dim3(256), 0, stream,
                       src, Wk1, Wv, Wk2, bias, valg, keyg);
    hipLaunchKernelGGL(skern, dim3(256), dim3(256), 0, stream, valg, keyg, Sbuf, Zbuf);
    hipLaunchKernelGGL(cvts, dim3(512), dim3(256), 0, stream, Sbuf, Sbf);
    hipLaunchKernelGGL(tgtAttn, dim3(256, 8), dim3(256), 0, stream,
                       tgt, Wq1, Wq2, bias, Sbf, Zbuf, (float*)d_out);
}